// Round 6
// baseline (950.740 us; speedup 1.0000x reference)
//
#include <hip/hip_runtime.h>

// ---------------------------------------------------------------------------
// MHSA (faithful: softmax over HEADS at each position).
//   cvt_all: one kernel converts q,k,v,Wq,Wk,Wv,Wo fp32->bf16
//   GEMM: 256x256 tile, 4 waves (1 wave/SIMD, ~440 VGPR), per-wave 128x128,
//         4 quadrant phases/K-tile with ONE-PHASE-AHEAD fragment pipelining
//         (reads for phase p+1 issue before phase p's MFMA cluster),
//         2 barriers + 2 counted vmcnt(8) per K-tile.
//   attention: per-position 16x16 softmax-over-heads + PV, permuted scatter
// ---------------------------------------------------------------------------

#define DEV __device__ __forceinline__

using short8  = __attribute__((ext_vector_type(8))) short;
using ushort8 = __attribute__((ext_vector_type(8))) unsigned short;
using f32x4   = __attribute__((ext_vector_type(4))) float;
using u16x8   = __attribute__((ext_vector_type(8))) unsigned short;

constexpr int BATCH = 4, SEQ = 4096, DIM = 2048;
constexpr int GM = BATCH * SEQ;   // 16384
constexpr int GN = DIM, GK = DIM; // 2048

DEV unsigned short f2bf(float f) {
  unsigned int u = __builtin_bit_cast(unsigned int, f);
  u += 0x7FFFu + ((u >> 16) & 1u);   // RNE
  return (unsigned short)(u >> 16);
}
DEV float bf2f(unsigned short h) {
  unsigned int u = ((unsigned int)h) << 16;
  return __builtin_bit_cast(float, u);
}

DEV void gload16(const void* g, void* l) {
  __builtin_amdgcn_global_load_lds(
      (const __attribute__((address_space(1))) void*)g,
      (__attribute__((address_space(3))) void*)l, 16, 0, 0);
}

#define BAR    __builtin_amdgcn_s_barrier()
#define LGKM0  asm volatile("s_waitcnt lgkmcnt(0)" ::: "memory")
#define LGKM(N) asm volatile("s_waitcnt lgkmcnt(" #N ")" ::: "memory")
#define VMC(N) asm volatile("s_waitcnt vmcnt(" #N ")" ::: "memory")
#define SCHED0 __builtin_amdgcn_sched_barrier(0)
#define PRIO1  __builtin_amdgcn_s_setprio(1)
#define PRIO0  __builtin_amdgcn_s_setprio(0)
#define MFMA16(a, b, c) __builtin_amdgcn_mfma_f32_16x16x32_bf16(a, b, c, 0, 0, 0)

// one quadrant: 4m x 4n frags x 2 k-slices = 32 MFMA (static acc indices)
#define QUAD(AF, BF, MO, NO)                                          \
  _Pragma("unroll") for (int m_ = 0; m_ < 4; ++m_)                    \
  _Pragma("unroll") for (int n_ = 0; n_ < 4; ++n_) {                  \
    acc[(MO) + m_][(NO) + n_] =                                       \
        MFMA16(AF[m_][0], BF[n_][0], acc[(MO) + m_][(NO) + n_]);      \
    acc[(MO) + m_][(NO) + n_] =                                       \
        MFMA16(AF[m_][1], BF[n_][1], acc[(MO) + m_][(NO) + n_]);      \
  }

// ---------------- fused fp32 -> bf16 conversion (7 tensors, 1 launch) -----
constexpr size_t NE_C = (size_t)GM * GK;   // 33,554,432 per activation
constexpr size_t WE_C = (size_t)GK * GN;   //  4,194,304 per weight

__global__ __launch_bounds__(256)
void cvt_all(const float* __restrict__ q, const float* __restrict__ k,
             const float* __restrict__ v, const float* __restrict__ Wq,
             const float* __restrict__ Wk, const float* __restrict__ Wv,
             const float* __restrict__ Wo,
             unsigned short* __restrict__ Qin, unsigned short* __restrict__ Kin,
             unsigned short* __restrict__ Vin, unsigned short* __restrict__ Wqb,
             unsigned short* __restrict__ Wkb, unsigned short* __restrict__ Wvb,
             unsigned short* __restrict__ Wob) {
  size_t gi = ((size_t)blockIdx.x * 256 + threadIdx.x) * 8;
  const float* src;
  unsigned short* dst;
  size_t off;
  if (gi < NE_C)            { src = q;  dst = Qin; off = gi; }
  else if (gi < 2 * NE_C)   { src = k;  dst = Kin; off = gi - NE_C; }
  else if (gi < 3 * NE_C)   { src = v;  dst = Vin; off = gi - 2 * NE_C; }
  else {
    size_t w = gi - 3 * NE_C;
    if (w < WE_C)           { src = Wq; dst = Wqb; off = w; }
    else if (w < 2 * WE_C)  { src = Wk; dst = Wkb; off = w - WE_C; }
    else if (w < 3 * WE_C)  { src = Wv; dst = Wvb; off = w - 2 * WE_C; }
    else                    { src = Wo; dst = Wob; off = w - 3 * WE_C; }
  }
  f32x4 f0 = *(const f32x4*)(src + off);
  f32x4 f1 = *(const f32x4*)(src + off + 4);
  ushort8 o;
#pragma unroll
  for (int j = 0; j < 4; ++j) { o[j] = f2bf(f0[j]); o[4 + j] = f2bf(f1[j]); }
  *(ushort8*)(dst + off) = o;
}

// ---------------- 256^2 4-wave pipelined GEMM: C = A*B^T + bias -----------
// LDS: As/Bs[2][256x64] bf16 = 128 KiB, XOR-swizzle byte^=((row&7)<<4).
// Wave (wm,wn) owns 128x128 output quadrant. Per K-tile, 4 phases:
//   P0: rd Bnhi(T);             lgkm(8); MFMA(al,bl)  -> acc[0:4][0:4]
//   P1: rd Amhi(T);             lgkm(8); MFMA(al,bh)  -> acc[0:4][4:8]
//   P2: lgkm0; vmc(8); BAR; stA(T+2)->cur; rd Amlo(T+1)<-nxt; MFMA(ah,bh)
//   P3: vmc(8|0); BAR; stB(T+2)->cur;      MFMA(ah,bl); rd Bnlo(T+1)<-nxt
// vmcnt audit: A(T+1),B(T+1) outstanding at tile start; P2 vmc(8) drains
// A(T+1) (oldest), P3 vmc(8) drains B(T+1), keeps A(T+2) flying.
template <bool OUTF32>
__global__ __launch_bounds__(256, 1)
void gemm256p(const unsigned short* __restrict__ Ap,
              const unsigned short* __restrict__ Bp,
              const float* __restrict__ bias, void* __restrict__ Cp) {
  constexpr int BK = 64, KT = GK / BK;   // 32 K-tiles
  __shared__ unsigned short As[2][256 * BK];
  __shared__ unsigned short Bs[2][256 * BK];

  const int tid  = threadIdx.x;
  const int lane = tid & 63;
  const int wv   = tid >> 6;
  const int wm   = wv >> 1, wn = wv & 1;

  // XCD-chunked mapping (proven: minimal FETCH)
  int bid = (int)blockIdx.x;
  const int xcd = bid & 7, rr = bid >> 3;
  const int gg = rr >> 5, jj = rr & 31;
  const int mt = xcd * 8 + gg * 4 + (jj & 3);
  const int nt = jj >> 2;
  const int bm0 = mt * 256, bn0 = nt * 256;

  // staging: 256 thr x 8 rounds x 16B covers one 256x64 bf16 tile (32KB)
  int offA[8];
#pragma unroll
  for (int r = 0; r < 8; ++r) {
    int d = tid * 16 + r * 4096;
    int s = d ^ (((d >> 7) & 7) << 4);
    int row = s >> 7, col = (s & 127) >> 1;
    offA[r] = (bm0 + row) * GK + col;
  }
  const int dAB = (bn0 - bm0) * GK;   // offB[r] = offA[r] + dAB

  const int r16 = lane & 15, kb = (lane >> 4) * 16;

  f32x4 acc[8][8] = {};
  short8 al[4][2], ah[4][2], bl[4][2], bh[4][2];

  auto stA = [&](int buf, int T) {
#pragma unroll
    for (int r = 0; r < 8; ++r)
      gload16(Ap + (size_t)offA[r] + (size_t)T * BK,
              (char*)&As[buf][0] + (tid * 16 + r * 4096));
  };
  auto stB = [&](int buf, int T) {
#pragma unroll
    for (int r = 0; r < 8; ++r)
      gload16(Bp + (size_t)(offA[r] + dAB) + (size_t)T * BK,
              (char*)&Bs[buf][0] + (tid * 16 + r * 4096));
  };
  auto ldf = [&](const unsigned short* base, int row, int ks) -> short8 {
    int a = (row * 128 + ks * 64 + kb) ^ ((row & 7) << 4);
    return *(const short8*)((const char*)base + a);
  };
  auto rdS = [&](short8 (&dst)[4][2], const unsigned short* base, int row0) {
#pragma unroll
    for (int m = 0; m < 4; ++m) {
      dst[m][0] = ldf(base, row0 + m * 16 + r16, 0);
      dst[m][1] = ldf(base, row0 + m * 16 + r16, 1);
    }
  };

  // ---- prologue ----
  stA(0, 0); stB(0, 0);
  VMC(0); SCHED0; BAR;
  stA(1, 1); stB(1, 1);            // A(1) then B(1): steady-state order
  rdS(al, &As[0][0], wm * 128);    // Amlo(0)
  rdS(bl, &Bs[0][0], wn * 128);    // Bnlo(0)

  for (int T = 0; T < KT; ++T) {
    const int bb = T & 1;
    const unsigned short* Ac = &As[bb][0];
    const unsigned short* Bc = &Bs[bb][0];
    const unsigned short* An = &As[bb ^ 1][0];
    const unsigned short* Bn = &Bs[bb ^ 1][0];
    const bool m1 = (T + 1 < KT), m2 = (T + 2 < KT);

    // ===== P0: MFMA(al,bl); prefetch bh =====
    rdS(bh, Bc, wn * 128 + 64);
    LGKM(8); SCHED0;               // drain al',bl' (keep bh flying)
    PRIO1; QUAD(al, bl, 0, 0); PRIO0;

    // ===== P1: MFMA(al,bh); prefetch ah =====
    rdS(ah, Ac, wm * 128 + 64);
    LGKM(8); SCHED0;               // drain bh
    PRIO1; QUAD(al, bh, 0, 4); PRIO0;

    // ===== P2: MFMA(ah,bh); stage A(T+2); prefetch al' =====
    LGKM0; SCHED0;                 // drain ah; all cur-buf reads done
    if (m1) {
      if (m2) { VMC(8); } else { VMC(0); }
      SCHED0; BAR;
      if (m2) stA(bb, T + 2);
      rdS(al, An, wm * 128);       // Amlo(T+1)
    }
    PRIO1; QUAD(ah, bh, 4, 4); PRIO0;

    // ===== P3: MFMA(ah,bl); stage B(T+2); prefetch bl' (after MFMA: WAR) ==
    if (m1) {
      if (m2) { VMC(8); } else { VMC(0); }
      SCHED0; BAR;
      if (m2) stB(bb, T + 2);
    }
    PRIO1; QUAD(ah, bl, 4, 0); PRIO0;
    if (m1) rdS(bl, Bn, wn * 128); // Bnlo(T+1) — overwrites bl after use
  }

  // ---- epilogue: C row=(lane>>4)*4+i, col=lane&15 (m89-verified) ----
  float bs[8];
#pragma unroll
  for (int n = 0; n < 8; ++n) bs[n] = bias[bn0 + wn * 128 + n * 16 + r16];
  const int rb = (lane >> 4) * 4;
#pragma unroll
  for (int m = 0; m < 8; ++m)
#pragma unroll
    for (int i = 0; i < 4; ++i) {
      const size_t row = (size_t)bm0 + wm * 128 + m * 16 + rb + i;
#pragma unroll
      for (int n = 0; n < 8; ++n) {
        const int col = bn0 + wn * 128 + n * 16 + r16;
        float v = acc[m][n][i] + bs[n];
        if constexpr (OUTF32)
          ((float*)Cp)[row * GN + col] = v;
        else
          ((unsigned short*)Cp)[row * GN + col] = f2bf(v);
      }
    }
}

// ---------------- per-position attention (softmax over heads) -------------
__global__ __launch_bounds__(256)
void attn_kernel(const unsigned short* __restrict__ Qb,
                 const unsigned short* __restrict__ Kb,
                 const unsigned short* __restrict__ Vb,
                 float* __restrict__ attnOut,
                 unsigned short* __restrict__ X2) {
  __shared__ float qf[16 * 128];
  __shared__ float kf[16 * 132];
  __shared__ float vf[16 * 128];
  __shared__ float sc[256];

  const int t = threadIdx.x;
  const int p = blockIdx.x;
  const size_t rowoff = (size_t)p * DIM;

  {
    const int e = t * 8;
    u16x8 qv = *(const u16x8*)(Qb + rowoff + e);
    u16x8 kv = *(const u16x8*)(Kb + rowoff + e);
    u16x8 vv = *(const u16x8*)(Vb + rowoff + e);
    const int r = t >> 4, c = (t & 15) * 8;
#pragma unroll
    for (int j = 0; j < 8; ++j) qf[r * 128 + c + j] = bf2f(qv[j]);
#pragma unroll
    for (int j = 0; j < 8; ++j) kf[r * 132 + c + j] = bf2f(kv[j]);
#pragma unroll
    for (int j = 0; j < 8; ++j) vf[r * 128 + c + j] = bf2f(vv[j]);
  }
  __syncthreads();

  const int i = t >> 4, j = t & 15;
  float s = 0.f;
#pragma unroll
  for (int d4 = 0; d4 < 32; ++d4) {
    f32x4 q4 = *(const f32x4*)&qf[i * 128 + d4 * 4];
    f32x4 k4 = *(const f32x4*)&kf[j * 132 + d4 * 4];
    s = fmaf(q4[0], k4[0], fmaf(q4[1], k4[1], fmaf(q4[2], k4[2], fmaf(q4[3], k4[3], s))));
  }
  s *= 0.08838834764831845f;

  float mx = s;
#pragma unroll
  for (int off = 8; off; off >>= 1) mx = fmaxf(mx, __shfl_xor(mx, off, 16));
  float ex = __expf(s - mx);
  float sum = ex;
#pragma unroll
  for (int off = 8; off; off >>= 1) sum += __shfl_xor(sum, off, 16);
  float a = ex / sum;

  attnOut[(size_t)p * 256 + t] = a;
  sc[t] = a;
  __syncthreads();

  const int dh0 = j * 8;
  float o[8] = {};
#pragma unroll
  for (int jjq = 0; jjq < 16; ++jjq) {
    float aij = sc[i * 16 + jjq];
#pragma unroll
    for (int e2 = 0; e2 < 8; ++e2)
      o[e2] = fmaf(aij, vf[jjq * 128 + dh0 + e2], o[e2]);
  }
  const int b = p >> 12, spos = p & 4095;
  const int row = i * 256 + (spos >> 4);
  const int col = ((spos & 15) << 7) + dh0;
  ushort8 pk;
#pragma unroll
  for (int e2 = 0; e2 < 8; ++e2) pk[e2] = f2bf(o[e2]);
  *(ushort8*)(X2 + (size_t)b * (SEQ * DIM) + (size_t)row * DIM + col) = pk;
}

// ---------------------------------------------------------------------------
extern "C" void kernel_launch(void* const* d_in, const int* in_sizes, int n_in,
                              void* d_out, int out_size, void* d_ws,
                              size_t ws_size, hipStream_t stream) {
  const float* q  = (const float*)d_in[0];
  const float* k  = (const float*)d_in[1];
  const float* v  = (const float*)d_in[2];
  const float* Wq = (const float*)d_in[3];
  const float* bq = (const float*)d_in[4];
  const float* Wk = (const float*)d_in[5];
  const float* bk = (const float*)d_in[6];
  const float* Wv = (const float*)d_in[7];
  const float* bv = (const float*)d_in[8];
  const float* Wo = (const float*)d_in[9];
  const float* bo = (const float*)d_in[10];

  const size_t NE = NE_C;
  const size_t WE = WE_C;

  unsigned short* ws16 = (unsigned short*)d_ws;
  unsigned short* Wq_b = ws16;
  unsigned short* Wk_b = Wq_b + WE;
  unsigned short* Wv_b = Wk_b + WE;
  unsigned short* Wo_b = Wv_b + WE;
  unsigned short* Qb   = Wo_b + WE;
  unsigned short* Kb   = Qb + NE;
  unsigned short* Vb   = Kb + NE;
  unsigned short* X2   = Vb + NE;
  unsigned short* Qin  = X2 + NE;
  unsigned short* Kin  = Qin + NE;
  unsigned short* Vin  = Kin + NE;

  float* outMain = (float*)d_out;
  float* attnOut = outMain + (size_t)GM * GN;

  // one fused convert launch: 3*NE + 4*WE elems, 8 per thread
  const int cvt_blocks = (int)((3 * NE + 4 * WE) / 8 / 256);   // 57344
  cvt_all<<<cvt_blocks, 256, 0, stream>>>(q, k, v, Wq, Wk, Wv, Wo,
                                          Qin, Kin, Vin, Wq_b, Wk_b, Wv_b, Wo_b);

  constexpr int G256 = (GM / 256) * (GN / 256);   // 512

  gemm256p<false><<<G256, 256, 0, stream>>>(Qin, Wq_b, bq, Qb);
  gemm256p<false><<<G256, 256, 0, stream>>>(Kin, Wk_b, bk, Kb);
  gemm256p<false><<<G256, 256, 0, stream>>>(Vin, Wv_b, bv, Vb);

  attn_kernel<<<GM, 256, 0, stream>>>(Qb, Kb, Vb, attnOut, X2);

  gemm256p<true><<<G256, 256, 0, stream>>>(X2, Wo_b, bo, outMain);
}

// Round 7
// 817.027 us; speedup vs baseline: 1.1637x; 1.1637x over previous
//
#include <hip/hip_runtime.h>

// ---------------------------------------------------------------------------
// MHSA (faithful: softmax over HEADS at each position).
//   prep: q,k,v fp32->bf16 linear; Wq..Wo fp32 -> bf16 MFMA-fragment order
//   GEMM: 128x128 tile, 4 waves, per-wave 64x64. A via tri-buffered LDS
//         (global_load_lds, XOR swizzle); B fragments DIRECT FROM L2
//         (pre-swizzled, coalesced dwordx4 per frag, inline asm + counted
//         vmcnt). 2 blocks/CU. One barrier + one VMC + 32 MFMA per K-tile.
//   attention: per-position 16x16 softmax-over-heads + PV, permuted scatter
// ---------------------------------------------------------------------------

#define DEV __device__ __forceinline__

using short8  = __attribute__((ext_vector_type(8))) short;
using ushort8 = __attribute__((ext_vector_type(8))) unsigned short;
using f32x4   = __attribute__((ext_vector_type(4))) float;
using u16x8   = __attribute__((ext_vector_type(8))) unsigned short;

constexpr int BATCH = 4, SEQ = 4096, DIM = 2048;
constexpr int GM = BATCH * SEQ;   // 16384
constexpr int GN = DIM, GK = DIM; // 2048

DEV unsigned short f2bf(float f) {
  unsigned int u = __builtin_bit_cast(unsigned int, f);
  u += 0x7FFFu + ((u >> 16) & 1u);   // RNE
  return (unsigned short)(u >> 16);
}
DEV float bf2f(unsigned short h) {
  unsigned int u = ((unsigned int)h) << 16;
  return __builtin_bit_cast(float, u);
}

DEV void gload16(const void* g, void* l) {
  __builtin_amdgcn_global_load_lds(
      (const __attribute__((address_space(1))) void*)g,
      (__attribute__((address_space(3))) void*)l, 16, 0, 0);
}

#define BAR    __builtin_amdgcn_s_barrier()
#define VMC(N) asm volatile("s_waitcnt vmcnt(" #N ")" ::: "memory")
#define SCHED0 __builtin_amdgcn_sched_barrier(0)
#define PRIO1  __builtin_amdgcn_s_setprio(1)
#define PRIO0  __builtin_amdgcn_s_setprio(0)
#define MFMA16(a, b, c) __builtin_amdgcn_mfma_f32_16x16x32_bf16(a, b, c, 0, 0, 0)

constexpr size_t NE_C = (size_t)GM * GK;   // 33,554,432
constexpr size_t WE_C = (size_t)GK * GN;   //  4,194,304

// ---------------- prep: activations linear cvt + weights frag-swizzle -----
// Bf layout: elem offset = (((nt*32 + kt)*2 + half)*8 + f)*512 + lane*8
//   f = nf*2 + ks; element (n,k): n = nt*128+half*64+nf*16+(lane&15),
//                                 k = kt*64+ks*32+(lane>>4)*8 + e
__global__ __launch_bounds__(256)
void prep(const float* __restrict__ q, const float* __restrict__ k,
          const float* __restrict__ v, const float* __restrict__ Wq,
          const float* __restrict__ Wk, const float* __restrict__ Wv,
          const float* __restrict__ Wo,
          unsigned short* __restrict__ Qin, unsigned short* __restrict__ Kin,
          unsigned short* __restrict__ Vin, unsigned short* __restrict__ Bq,
          unsigned short* __restrict__ Bk, unsigned short* __restrict__ Bv,
          unsigned short* __restrict__ Bo) {
  const int bid = blockIdx.x;
  if (bid < 49152) {                       // 3 x 16384 activation blocks
    const int tens = bid >> 14;
    const size_t off = ((size_t)(bid & 16383) * 256 + threadIdx.x) * 8;
    const float* s = tens == 0 ? q : tens == 1 ? k : v;
    unsigned short* d = tens == 0 ? Qin : tens == 1 ? Kin : Vin;
    f32x4 f0 = *(const f32x4*)(s + off);
    f32x4 f1 = *(const f32x4*)(s + off + 4);
    ushort8 o;
#pragma unroll
    for (int j = 0; j < 4; ++j) { o[j] = f2bf(f0[j]); o[4 + j] = f2bf(f1[j]); }
    *(ushort8*)(d + off) = o;
  } else {                                 // 4 x 2048 weight blocks
    const int wb = bid - 49152;
    const int w = wb >> 11;
    const int t = (wb & 2047) * 256 + threadIdx.x;   // 0..524287
    const float* W = w == 0 ? Wq : w == 1 ? Wk : w == 2 ? Wv : Wo;
    unsigned short* D = w == 0 ? Bq : w == 1 ? Bk : w == 2 ? Bv : Bo;
    const int lane = t & 63, f = (t >> 6) & 7, half = (t >> 9) & 1;
    const int kt = (t >> 10) & 31, nt = t >> 15;
    const int n  = nt * 128 + half * 64 + (f >> 1) * 16 + (lane & 15);
    const int kk = kt * 64 + (f & 1) * 32 + (lane >> 4) * 8;
    const float* sp = W + (size_t)n * GK + kk;
    f32x4 f0 = *(const f32x4*)sp;
    f32x4 f1 = *(const f32x4*)(sp + 4);
    ushort8 o;
#pragma unroll
    for (int j = 0; j < 4; ++j) { o[j] = f2bf(f0[j]); o[4 + j] = f2bf(f1[j]); }
    *(ushort8*)(D + (size_t)t * 8) = o;
  }
}

// ---------------- 128^2 4-wave GEMM, B-direct-from-L2 ---------------------
template <bool OUTF32>
__global__ __launch_bounds__(256, 2)
void gemm128d(const unsigned short* __restrict__ Ap,
              const unsigned short* __restrict__ Bf,
              const float* __restrict__ bias, void* __restrict__ Cp) {
  constexpr int BK = 64, KT = GK / BK;     // 32 K-tiles
  __shared__ unsigned short As[3][128 * 64];   // 48KB tri-buffer

  const int tid  = threadIdx.x;
  const int lane = tid & 63;
  const int wv   = tid >> 6;
  const int wm   = wv >> 1, wn = wv & 1;

  // XCD-chunked: window 8mt x 8nt per XCD (A 4MB + B 4MB, both L2-fit)
  const int bid = (int)blockIdx.x;
  const int xcd = bid & 7, rr = bid >> 3;
  const int gg = rr >> 6, jj = rr & 63;
  const int mt = xcd * 16 + (gg >> 1) * 8 + (jj & 7);
  const int nt = (gg & 1) * 8 + (jj >> 3);
  const int bm0 = mt * 128, bn0 = nt * 128;

  // A staging: 4 rounds x 4KB; dest linear, source pre-unswizzled
  int offA[4];
#pragma unroll
  for (int r = 0; r < 4; ++r) {
    int d = tid * 16 + r * 4096;
    int s = d ^ (((d >> 7) & 7) << 4);
    offA[r] = (bm0 + (s >> 7)) * GK + ((s & 127) >> 1);
  }
  const int r16 = lane & 15, kb = (lane >> 4) * 16;

  // B fragment base for this wave's (nt, wn) 64-col half
  const unsigned short* Bw =
      Bf + (size_t)nt * KT * 8192 + (size_t)wn * 4096 + (size_t)lane * 8;

  f32x4 acc[4][4] = {};
  short8 afA[4][2], afB[4][2], bA[4][2], bB[4][2];

  auto stA = [&](int bufoff, int T) {
#pragma unroll
    for (int r = 0; r < 4; ++r)
      gload16(Ap + (size_t)offA[r] + (size_t)T * BK,
              (char*)&As[0][0] + bufoff + (tid * 16 + r * 4096));
  };
  auto loadB = [&](short8 (&b)[4][2], int T) {
    const unsigned short* p = Bw + (size_t)T * 8192;
#pragma unroll
    for (int f = 0; f < 8; ++f) {
      asm volatile("global_load_dwordx4 %0, %1, off"
                   : "=v"(b[f >> 1][f & 1]) : "v"(p + f * 512) : "memory");
    }
  };
  auto rdA = [&](short8 (&a)[4][2], int bufoff) {
#pragma unroll
    for (int m = 0; m < 4; ++m)
#pragma unroll
      for (int ks = 0; ks < 2; ++ks) {
        int row = wm * 64 + m * 16 + r16;
        int ad = (row * 128 + ks * 64 + kb) ^ ((row & 7) << 4);
        a[m][ks] = *(const short8*)((const char*)&As[0][0] + bufoff + ad);
      }
  };
  auto cluster = [&](short8 (&a)[4][2], short8 (&b)[4][2]) {
    PRIO1;
#pragma unroll
    for (int m = 0; m < 4; ++m)
#pragma unroll
      for (int n = 0; n < 4; ++n) {
        acc[m][n] = MFMA16(a[m][0], b[n][0], acc[m][n]);
        acc[m][n] = MFMA16(a[m][1], b[n][1], acc[m][n]);
      }
    PRIO0;
  };

  // body(T): issue B(T+1); stage A(T+2); VMC; BAR; prefetch af(T+1); MFMA(T)
  auto body = [&](int T, short8 (&cb)[4][2], short8 (&nb)[4][2],
                  short8 (&ca)[4][2], short8 (&na)[4][2],
                  int bufn, int bufs) {
    if (T + 1 < KT) loadB(nb, T + 1);
    SCHED0;
    if (T + 2 < KT) stA(bufs, T + 2);
    SCHED0;
    // drain A(T+1)+B(T) and older; keep newest [B(T+1), A(T+2)]
    if (T + 2 < KT)      { VMC(12); }
    else if (T + 1 < KT) { VMC(8); }
    else                 { VMC(0); }
    SCHED0;
    if (T + 1 < KT) {
      BAR; SCHED0;
      rdA(na, bufn);
      SCHED0;
    }
    cluster(ca, cb);
  };

  // ---- prologue: A(0)->buf0, A(1)->buf1, B(0) ----
  stA(0, 0); stA(16384, 1);
  loadB(bA, 0);
  SCHED0; VMC(12); SCHED0;   // A(0) resident; A(1)+B(0) in flight
  BAR; SCHED0;
  rdA(afA, 0);
  SCHED0;

  int b0 = 0, b1 = 16384, b2 = 32768;   // cur, next, stage LDS offsets
  for (int T = 0; T < KT; T += 2) {
    body(T,     bA, bB, afA, afB, b1, b2);
    body(T + 1, bB, bA, afB, afA, b2, b0);
    int tmp = b2; b2 = b1; b1 = b0; b0 = tmp;   // shift left by 2 (mod 3)
  }

  // ---- epilogue: C row=(lane>>4)*4+i, col=lane&15 (m89-verified) ----
  float bs[4];
#pragma unroll
  for (int n = 0; n < 4; ++n) bs[n] = bias[bn0 + wn * 64 + n * 16 + r16];
  const int rb = (lane >> 4) * 4;
#pragma unroll
  for (int m = 0; m < 4; ++m)
#pragma unroll
    for (int i = 0; i < 4; ++i) {
      const size_t row = (size_t)bm0 + wm * 64 + m * 16 + rb + i;
#pragma unroll
      for (int n = 0; n < 4; ++n) {
        const int col = bn0 + wn * 64 + n * 16 + r16;
        float val = acc[m][n][i] + bs[n];
        if constexpr (OUTF32)
          ((float*)Cp)[row * GN + col] = val;
        else
          ((unsigned short*)Cp)[row * GN + col] = f2bf(val);
      }
    }
}

// ---------------- per-position attention (softmax over heads) -------------
__global__ __launch_bounds__(256)
void attn_kernel(const unsigned short* __restrict__ Qb,
                 const unsigned short* __restrict__ Kb,
                 const unsigned short* __restrict__ Vb,
                 float* __restrict__ attnOut,
                 unsigned short* __restrict__ X2) {
  __shared__ float qf[16 * 128];
  __shared__ float kf[16 * 132];
  __shared__ float vf[16 * 128];
  __shared__ float sc[256];

  const int t = threadIdx.x;
  const int p = blockIdx.x;
  const size_t rowoff = (size_t)p * DIM;

  {
    const int e = t * 8;
    u16x8 qv = *(const u16x8*)(Qb + rowoff + e);
    u16x8 kv = *(const u16x8*)(Kb + rowoff + e);
    u16x8 vv = *(const u16x8*)(Vb + rowoff + e);
    const int r = t >> 4, c = (t & 15) * 8;
#pragma unroll
    for (int j = 0; j < 8; ++j) qf[r * 128 + c + j] = bf2f(qv[j]);
#pragma unroll
    for (int j = 0; j < 8; ++j) kf[r * 132 + c + j] = bf2f(kv[j]);
#pragma unroll
    for (int j = 0; j < 8; ++j) vf[r * 128 + c + j] = bf2f(vv[j]);
  }
  __syncthreads();

  const int i = t >> 4, j = t & 15;
  float s = 0.f;
#pragma unroll
  for (int d4 = 0; d4 < 32; ++d4) {
    f32x4 q4 = *(const f32x4*)&qf[i * 128 + d4 * 4];
    f32x4 k4 = *(const f32x4*)&kf[j * 132 + d4 * 4];
    s = fmaf(q4[0], k4[0], fmaf(q4[1], k4[1], fmaf(q4[2], k4[2], fmaf(q4[3], k4[3], s))));
  }
  s *= 0.08838834764831845f;

  float mx = s;
#pragma unroll
  for (int off = 8; off; off >>= 1) mx = fmaxf(mx, __shfl_xor(mx, off, 16));
  float ex = __expf(s - mx);
  float sum = ex;
#pragma unroll
  for (int off = 8; off; off >>= 1) sum += __shfl_xor(sum, off, 16);
  float a = ex / sum;

  attnOut[(size_t)p * 256 + t] = a;
  sc[t] = a;
  __syncthreads();

  const int dh0 = j * 8;
  float o[8] = {};
#pragma unroll
  for (int jjq = 0; jjq < 16; ++jjq) {
    float aij = sc[i * 16 + jjq];
#pragma unroll
    for (int e2 = 0; e2 < 8; ++e2)
      o[e2] = fmaf(aij, vf[jjq * 128 + dh0 + e2], o[e2]);
  }
  const int b = p >> 12, spos = p & 4095;
  const int row = i * 256 + (spos >> 4);
  const int col = ((spos & 15) << 7) + dh0;
  ushort8 pk;
#pragma unroll
  for (int e2 = 0; e2 < 8; ++e2) pk[e2] = f2bf(o[e2]);
  *(ushort8*)(X2 + (size_t)b * (SEQ * DIM) + (size_t)row * DIM + col) = pk;
}

// ---------------------------------------------------------------------------
extern "C" void kernel_launch(void* const* d_in, const int* in_sizes, int n_in,
                              void* d_out, int out_size, void* d_ws,
                              size_t ws_size, hipStream_t stream) {
  const float* q  = (const float*)d_in[0];
  const float* k  = (const float*)d_in[1];
  const float* v  = (const float*)d_in[2];
  const float* Wq = (const float*)d_in[3];
  const float* bq = (const float*)d_in[4];
  const float* Wk = (const float*)d_in[5];
  const float* bk = (const float*)d_in[6];
  const float* Wv = (const float*)d_in[7];
  const float* bv = (const float*)d_in[8];
  const float* Wo = (const float*)d_in[9];
  const float* bo = (const float*)d_in[10];

  const size_t NE = NE_C, WE = WE_C;

  unsigned short* ws16 = (unsigned short*)d_ws;
  unsigned short* Bq_f = ws16;              // frag-swizzled weights
  unsigned short* Bk_f = Bq_f + WE;
  unsigned short* Bv_f = Bk_f + WE;
  unsigned short* Bo_f = Bv_f + WE;
  unsigned short* Qb   = Bo_f + WE;
  unsigned short* Kb   = Qb + NE;
  unsigned short* Vb   = Kb + NE;
  unsigned short* X2   = Vb + NE;
  unsigned short* Qin  = X2 + NE;
  unsigned short* Kin  = Qin + NE;
  unsigned short* Vin  = Kin + NE;

  float* outMain = (float*)d_out;
  float* attnOut = outMain + (size_t)GM * GN;

  prep<<<57344, 256, 0, stream>>>(q, k, v, Wq, Wk, Wv, Wo,
                                  Qin, Kin, Vin, Bq_f, Bk_f, Bv_f, Bo_f);

  constexpr int G128 = (GM / 128) * (GN / 128);   // 2048

  gemm128d<false><<<G128, 256, 0, stream>>>(Qin, Bq_f, bq, Qb);
  gemm128d<false><<<G128, 256, 0, stream>>>(Kin, Bk_f, bk, Kb);
  gemm128d<false><<<G128, 256, 0, stream>>>(Vin, Bv_f, bv, Vb);

  attn_kernel<<<GM, 256, 0, stream>>>(Qb, Kb, Vb, attnOut, X2);

  gemm128d<true><<<G128, 256, 0, stream>>>(X2, Bo_f, bo, outMain);
}